// Round 2
// baseline (1755.171 us; speedup 1.0000x reference)
//
#include <hip/hip_runtime.h>

#define S 2048
#define HID 5120
#define NH 40
#define HD 128

typedef unsigned short u16;
typedef __attribute__((ext_vector_type(8))) short short8;
typedef __attribute__((ext_vector_type(4))) float f32x4;

__device__ __forceinline__ u16 f2bf(float f) {
  union { float f; unsigned u; } x; x.f = f;
  unsigned r = x.u + 0x7fffu + ((x.u >> 16) & 1u);
  return (u16)(r >> 16);
}

// async global->LDS, 16B per lane; LDS dest = wave-uniform base + lane*16
__device__ __forceinline__ void gl_lds16(const void* g, void* l) {
  __builtin_amdgcn_global_load_lds((__attribute__((address_space(1))) void*)g,
                                   (__attribute__((address_space(3))) void*)l,
                                   16, 0, 0);
}

// ---------------- fp32 -> bf16 convert ----------------
__global__ __launch_bounds__(256) void cvt4(const float4* __restrict__ s,
                                            ushort4* __restrict__ d, int n4) {
  int i = blockIdx.x * 256 + threadIdx.x;
  if (i >= n4) return;
  float4 v = s[i];
  ushort4 o;
  o.x = f2bf(v.x); o.y = f2bf(v.y); o.z = f2bf(v.z); o.w = f2bf(v.w);
  d[i] = o;
}

// ---------------- bf16 GEMM: C[M,N] = A[M,K] * B[N,K]^T ----------------
// (unchanged from round 1 — isolation)
__global__ __launch_bounds__(256) void gemm_bt(
    const u16* __restrict__ A, const u16* __restrict__ B,
    int N, int K,
    float* __restrict__ C,
    u16* __restrict__ qb, u16* __restrict__ kb, u16* __restrict__ vtb,
    int mode)
{
  __shared__ __align__(16) u16 As[128 * 64];
  __shared__ __align__(16) u16 Bs[128 * 64];
  const int tid = threadIdx.x;
  const int lane = tid & 63;
  const int wid = tid >> 6;
  const int wm = wid >> 1, wn = wid & 1;
  const int l16 = lane & 15, quad = lane >> 4;
  const int m0 = blockIdx.x * 128, n0 = blockIdx.y * 128;

  f32x4 acc[4][4];
#pragma unroll
  for (int i = 0; i < 4; ++i)
#pragma unroll
    for (int j = 0; j < 4; ++j)
      acc[i][j] = (f32x4){0.f, 0.f, 0.f, 0.f};

  const int srow = lane >> 3;
  const int scb = lane & 7;

  for (int k0 = 0; k0 < K; k0 += 64) {
#pragma unroll
    for (int cc = 0; cc < 4; ++cc) {
      int c = wid * 4 + cc;
      int row = c * 8 + srow;
      int cb = scb ^ (row & 7);
      gl_lds16(A + (long)(m0 + row) * K + k0 + cb * 8, &As[c * 512]);
    }
#pragma unroll
    for (int cc = 0; cc < 4; ++cc) {
      int c = wid * 4 + cc;
      int row = c * 8 + srow;
      int cb = scb ^ (row & 7);
      gl_lds16(B + (long)(n0 + row) * K + k0 + cb * 8, &Bs[c * 512]);
    }
    __syncthreads();
#pragma unroll
    for (int kk = 0; kk < 64; kk += 32) {
      short8 af[4], bg[4];
      const int cb0 = (kk >> 3) + quad;
#pragma unroll
      for (int i = 0; i < 4; ++i) {
        int row = wm * 64 + i * 16 + l16;
        af[i] = *(const short8*)&As[row * 64 + (cb0 ^ (row & 7)) * 8];
      }
#pragma unroll
      for (int j = 0; j < 4; ++j) {
        int row = wn * 64 + j * 16 + l16;
        bg[j] = *(const short8*)&Bs[row * 64 + (cb0 ^ (row & 7)) * 8];
      }
#pragma unroll
      for (int i = 0; i < 4; ++i)
#pragma unroll
        for (int j = 0; j < 4; ++j)
          acc[i][j] = __builtin_amdgcn_mfma_f32_16x16x32_bf16(af[i], bg[j], acc[i][j], 0, 0, 0);
    }
    __syncthreads();
  }

  if (mode == 0) {
#pragma unroll
    for (int i = 0; i < 4; ++i)
#pragma unroll
      for (int r = 0; r < 4; ++r) {
        int row = m0 + wm * 64 + i * 16 + quad * 4 + r;
#pragma unroll
        for (int j = 0; j < 4; ++j) {
          int col = n0 + wn * 64 + j * 16 + l16;
          C[(long)row * N + col] = acc[i][j][r];
        }
      }
  } else {
    const int which = n0 / HID;
    const int head = (n0 % HID) >> 7;
    const float qs = 0.08838834764831845f;  // 1/sqrt(128)
#pragma unroll
    for (int i = 0; i < 4; ++i)
#pragma unroll
      for (int j = 0; j < 4; ++j)
#pragma unroll
        for (int r = 0; r < 4; ++r) {
          int sI = m0 + wm * 64 + i * 16 + quad * 4 + r;
          int d = wn * 64 + j * 16 + l16;
          float v = acc[i][j][r];
          if (which == 0)      qb[((long)head * S + sI) * HD + d] = f2bf(v * qs);
          else if (which == 1) kb[((long)head * S + sI) * HD + d] = f2bf(v);
          else                 vtb[((long)head * HD + d) * S + sI] = f2bf(v);
        }
  }
}

// ---------------- flash attention v2: barrier-free, wave-autonomous ----------------
// Each wave owns 32 q-rows. Q/K/V frags loaded straight from global (L2-served).
// Only LDS: wave-private P round-trip (C-layout -> A-layout), 4 KB/wave.
// q,k: [NH][S][HD] bf16 (q pre-scaled by 1/sqrt(HD)), v: [NH][HD][S] bf16 (V^T).
// out: [S][HID] bf16.
__global__ __launch_bounds__(256, 2) void attn_kernel(
    const u16* __restrict__ qg, const u16* __restrict__ kg,
    const u16* __restrict__ vg, u16* __restrict__ og)
{
  __shared__ __align__(16) u16 Ps[4][32 * 64];

  const int tid = threadIdx.x;
  const int lane = tid & 63;
  const int wid = tid >> 6;
  const int l16 = lane & 15, quad = lane >> 4;
  const int bq = 15 - blockIdx.x;              // long blocks dispatch first
  const int h = blockIdx.y;
  const int q0 = bq * 128 + wid * 32;          // this wave's 32 q-rows

  u16* P = &Ps[wid][0];

  // ---- Q fragments, A-layout, direct from global (one dwordx4 per frag) ----
  short8 qf[2][4];
#pragma unroll
  for (int i = 0; i < 2; ++i)
#pragma unroll
    for (int kk = 0; kk < 4; ++kk)
      qf[i][kk] = *(const short8*)(qg + ((long)h * S + q0 + i * 16 + l16) * HD
                                   + kk * 32 + quad * 8);

  f32x4 acc_o[2][8];
#pragma unroll
  for (int i = 0; i < 2; ++i)
#pragma unroll
    for (int j = 0; j < 8; ++j)
      acc_o[i][j] = (f32x4){0.f, 0.f, 0.f, 0.f};
  float m_st[2][4], l_st[2][4];
#pragma unroll
  for (int i = 0; i < 2; ++i)
#pragma unroll
    for (int r = 0; r < 4; ++r) { m_st[i][r] = -1e30f; l_st[i][r] = 0.f; }

  const int nkt = (q0 + 32 + 63) >> 6;         // K-tiles 0..nkt-1 (last is masked)

  for (int kt = 0; kt < nkt; ++kt) {
    // ---- S = Q K^T : 32x64, K frags direct from global ----
    f32x4 acc_s[2][4];
#pragma unroll
    for (int i = 0; i < 2; ++i)
#pragma unroll
      for (int j = 0; j < 4; ++j)
        acc_s[i][j] = (f32x4){0.f, 0.f, 0.f, 0.f};

    short8 kf[4][4];
#pragma unroll
    for (int j = 0; j < 4; ++j)
#pragma unroll
      for (int kk = 0; kk < 4; ++kk)
        kf[j][kk] = *(const short8*)(kg + ((long)h * S + kt * 64 + j * 16 + l16) * HD
                                     + kk * 32 + quad * 8);
#pragma unroll
    for (int kk = 0; kk < 4; ++kk)
#pragma unroll
      for (int i = 0; i < 2; ++i)
#pragma unroll
        for (int j = 0; j < 4; ++j)
          acc_s[i][j] = __builtin_amdgcn_mfma_f32_16x16x32_bf16(qf[i][kk], kf[j][kk],
                                                                acc_s[i][j], 0, 0, 0);

    // ---- causal mask: only the last tile can touch the diagonal ----
    if (kt == nkt - 1) {
#pragma unroll
      for (int i = 0; i < 2; ++i)
#pragma unroll
        for (int j = 0; j < 4; ++j)
#pragma unroll
          for (int r = 0; r < 4; ++r) {
            int row = q0 + i * 16 + quad * 4 + r;
            int col = kt * 64 + j * 16 + l16;
            if (col > row) acc_s[i][j][r] = -1e30f;
          }
    }

    // ---- in-wave row max (rows live entirely within a 16-lane group) ----
    float alpha[2][4], mnew[2][4], psum[2][4];
#pragma unroll
    for (int i = 0; i < 2; ++i)
#pragma unroll
      for (int r = 0; r < 4; ++r) {
        float v = fmaxf(fmaxf(acc_s[i][0][r], acc_s[i][1][r]),
                        fmaxf(acc_s[i][2][r], acc_s[i][3][r]));
        v = fmaxf(v, __shfl_xor(v, 1));
        v = fmaxf(v, __shfl_xor(v, 2));
        v = fmaxf(v, __shfl_xor(v, 4));
        v = fmaxf(v, __shfl_xor(v, 8));
        float mn = fmaxf(m_st[i][r], v);
        mnew[i][r] = mn;
        alpha[i][r] = __expf(m_st[i][r] - mn);
        m_st[i][r] = mn;
        psum[i][r] = 0.f;
      }

    // ---- P = exp(S - mnew) -> wave-private swizzled LDS (A-layout source) ----
#pragma unroll
    for (int i = 0; i < 2; ++i)
#pragma unroll
      for (int j = 0; j < 4; ++j)
#pragma unroll
        for (int r = 0; r < 4; ++r) {
          int lr = i * 16 + quad * 4 + r;
          int lc = j * 16 + l16;
          float p = __expf(acc_s[i][j][r] - mnew[i][r]);
          psum[i][r] += p;
          P[lr * 64 + (((lc >> 3) ^ (lr & 7)) << 3) + (lc & 7)] = f2bf(p);
        }

    // ---- in-wave row sum; rescale O; update l ----
#pragma unroll
    for (int i = 0; i < 2; ++i)
#pragma unroll
      for (int r = 0; r < 4; ++r) {
        float v = psum[i][r];
        v += __shfl_xor(v, 1);
        v += __shfl_xor(v, 2);
        v += __shfl_xor(v, 4);
        v += __shfl_xor(v, 8);
        l_st[i][r] = alpha[i][r] * l_st[i][r] + v;
#pragma unroll
        for (int j = 0; j < 8; ++j)
          acc_o[i][j][r] *= alpha[i][r];
      }

    // ---- O += P * V : V^T frags direct from global ----
#pragma unroll
    for (int kk = 0; kk < 64; kk += 32) {
      short8 ap[2];
      const int cb0 = (kk >> 3) + quad;
#pragma unroll
      for (int i = 0; i < 2; ++i) {
        int m = i * 16 + l16;
        ap[i] = *(const short8*)&P[m * 64 + ((cb0 ^ (m & 7)) << 3)];
      }
#pragma unroll
      for (int j = 0; j < 8; ++j) {
        short8 bv = *(const short8*)(vg + ((long)h * HD + j * 16 + l16) * S
                                     + kt * 64 + kk + quad * 8);
#pragma unroll
        for (int i = 0; i < 2; ++i)
          acc_o[i][j] = __builtin_amdgcn_mfma_f32_16x16x32_bf16(ap[i], bv,
                                                                acc_o[i][j], 0, 0, 0);
      }
    }
  }

  // ---- epilogue: O / l -> bf16 [S][HID] ----
#pragma unroll
  for (int i = 0; i < 2; ++i)
#pragma unroll
    for (int r = 0; r < 4; ++r) {
      float inv = 1.f / l_st[i][r];
      int row = q0 + i * 16 + quad * 4 + r;
#pragma unroll
      for (int j = 0; j < 8; ++j) {
        int d = j * 16 + l16;
        og[(long)row * HID + h * HD + d] = f2bf(acc_o[i][j][r] * inv);
      }
    }
}

// ---------------- host ----------------
extern "C" void kernel_launch(void* const* d_in, const int* in_sizes, int n_in,
                              void* d_out, int out_size, void* d_ws, size_t ws_size,
                              hipStream_t stream) {
  const float* hs = (const float*)d_in[0];
  const float* wp = (const float*)d_in[1];
  const float* wo = (const float*)d_in[2];
  float* out = (float*)d_out;
  char* ws = (char*)d_ws;

  u16* hsb = (u16*)(ws);                  //  20,971,520  hs bf16 [2048][5120]
  u16* wpb = (u16*)(ws + 20971520L);      // 157,286,400  W_pack bf16 [15360][5120]
  u16* wob = (u16*)(ws + 178257920L);     //  52,428,800  o_proj bf16 [5120][5120]
  u16* qb  = (u16*)(ws + 230686720L);     //  20,971,520  q bf16 [40][2048][128] (scaled)
  u16* kb  = (u16*)(ws + 251658240L);     //  20,971,520  k bf16 [40][2048][128]
  u16* vtb = (u16*)(ws + 272629760L);     //  20,971,520  v^T bf16 [40][128][2048]
  u16* aob = (u16*)(ws + 293601280L);     //  20,971,520  attn out bf16 [2048][5120]
  if (ws_size < 314572800UL) return;

  cvt4<<<10240, 256, 0, stream>>>((const float4*)hs, (ushort4*)hsb, 2621440);
  cvt4<<<76800, 256, 0, stream>>>((const float4*)wp, (ushort4*)wpb, 19660800);
  cvt4<<<25600, 256, 0, stream>>>((const float4*)wo, (ushort4*)wob, 6553600);

  gemm_bt<<<dim3(16, 120), 256, 0, stream>>>(hsb, wpb, 15360, 5120,
                                             nullptr, qb, kb, vtb, 1);
  attn_kernel<<<dim3(16, 40), 256, 0, stream>>>(qb, kb, vtb, aob);
  gemm_bt<<<dim3(16, 40), 256, 0, stream>>>(aob, wob, 5120, 5120,
                                            out, nullptr, nullptr, nullptr, 0);
}